// Round 2
// baseline (145.596 us; speedup 1.0000x reference)
//
#include <hip/hip_runtime.h>

// out[i, :] = weight[b[i], :]  (float32, Y_DIM=32), with out[0, :] = 0.
// 8 float4 chunks per cell; grid-stride so each thread handles ~2 chunks.
// Nontemporal stores: 128 MB output stream >> 32 MB L2, don't pollute it.

typedef float vfloat4 __attribute__((ext_vector_type(4)));

__global__ __launch_bounds__(256) void batch_effect_gather_kernel(
        const int* __restrict__ b,
        const vfloat4* __restrict__ w4,   // weight as [N_BATCHES, 8] float4
        vfloat4* __restrict__ out4,       // output as [N, 8] float4
        int n_vec) {                      // N * 8
    int stride = gridDim.x * 256;
    for (int g = blockIdx.x * 256 + threadIdx.x; g < n_vec; g += stride) {
        int cell = g >> 3;       // which cell
        int j    = g & 7;        // which float4 within the row
        int batch = b[cell];     // 8 lanes share one dword -> one transaction
        vfloat4 v = w4[batch * 8 + j];   // 8 KB table, L1-resident
        if (cell == 0) v = (vfloat4){0.f, 0.f, 0.f, 0.f};
        __builtin_nontemporal_store(v, &out4[g]);
    }
}

extern "C" void kernel_launch(void* const* d_in, const int* in_sizes, int n_in,
                              void* d_out, int out_size, void* d_ws, size_t ws_size,
                              hipStream_t stream) {
    const int*     b  = (const int*)d_in[0];      // [N, 1] int32
    const vfloat4* w4 = (const vfloat4*)d_in[1];  // [64, 32] f32 -> [64, 8] f4
    vfloat4* out4 = (vfloat4*)d_out;              // [N, 32] f32 -> [N, 8] f4

    int n = in_sizes[0];                 // N
    int n_vec = n * 8;                   // total float4 chunks
    int threads_wanted = (n_vec + 1) / 2;            // ~2 chunks per thread
    int blocks = (threads_wanted + 255) / 256;       // = 15625 for N=1e6
    batch_effect_gather_kernel<<<blocks, 256, 0, stream>>>(b, w4, out4, n_vec);
}

// Round 3
// 143.914 us; speedup vs baseline: 1.0117x; 1.0117x over previous
//
#include <hip/hip_runtime.h>

// out[i, :] = weight[b[i], :]  (float32, Y_DIM=32), with out[0, :] = 0.
// 4 threads per cell; thread t handles float4 chunks (t&3) and (t&3)+4 of
// cell t>>2. Per store-instruction a wave writes 16 FULL 64B cache lines
// (lanes 0-3 -> bytes 0..63 of one row), no partial lines. Each thread
// loads b[cell] once for 32 B of output (was once per 16 B).
// Nontemporal: 128 MB output stream >> 32 MB L2.

typedef float vfloat4 __attribute__((ext_vector_type(4)));

__global__ __launch_bounds__(256) void batch_effect_gather_kernel(
        const int* __restrict__ b,
        const vfloat4* __restrict__ w4,   // weight as [N_BATCHES, 8] float4
        vfloat4* __restrict__ out4,       // output as [N, 8] float4
        int n_threads) {                  // N * 4
    int t = blockIdx.x * 256 + threadIdx.x;
    if (t >= n_threads) return;
    int cell = t >> 2;        // which cell
    int j    = t & 3;         // chunk pair: j and j+4
    int batch = b[cell];      // 4 lanes share one dword
    vfloat4 v0 = w4[batch * 8 + j];       // 8 KB table, L1-resident
    vfloat4 v1 = w4[batch * 8 + j + 4];
    if (cell == 0) {
        v0 = (vfloat4){0.f, 0.f, 0.f, 0.f};
        v1 = (vfloat4){0.f, 0.f, 0.f, 0.f};
    }
    __builtin_nontemporal_store(v0, &out4[cell * 8 + j]);
    __builtin_nontemporal_store(v1, &out4[cell * 8 + j + 4]);
}

extern "C" void kernel_launch(void* const* d_in, const int* in_sizes, int n_in,
                              void* d_out, int out_size, void* d_ws, size_t ws_size,
                              hipStream_t stream) {
    const int*     b  = (const int*)d_in[0];      // [N, 1] int32
    const vfloat4* w4 = (const vfloat4*)d_in[1];  // [64, 32] f32 -> [64, 8] f4
    vfloat4* out4 = (vfloat4*)d_out;              // [N, 32] f32 -> [N, 8] f4

    int n = in_sizes[0];                  // N
    int n_threads = n * 4;                // 4 threads per cell
    int blocks = (n_threads + 255) / 256; // 15625 for N=1e6
    batch_effect_gather_kernel<<<blocks, 256, 0, stream>>>(b, w4, out4, n_threads);
}